// Round 1
// baseline (2004.168 us; speedup 1.0000x reference)
//
#include <hip/hip_runtime.h>

// GNNPolicy forward: 2-layer GCN (edge-weighted, symmetric norm, self-loops)
// + per-node actor head + per-graph mean-pool critic head.
// All f32. N=batch nodes, E edges, H=64 hidden, G=64 graphs.

#define TB 256

__global__ void deg_accum_k(const int* __restrict__ col, const float* __restrict__ ea,
                            float* __restrict__ deg, int E) {
    int e = blockIdx.x * blockDim.x + threadIdx.x;
    if (e < E) atomicAdd(&deg[col[e]], fabsf(ea[e]));
}

__global__ void dis_k(float* __restrict__ deg, int N) {
    int i = blockIdx.x * blockDim.x + threadIdx.x;
    if (i < N) deg[i] = rsqrtf(deg[i] + 1.0f);   // deg>=1 always (self-loop)
}

__global__ void norm_k(const int* __restrict__ row, const int* __restrict__ col,
                       const float* __restrict__ ea, const float* __restrict__ dis,
                       float* __restrict__ norm, int E) {
    int e = blockIdx.x * blockDim.x + threadIdx.x;
    if (e < E) norm[e] = dis[row[e]] * fabsf(ea[e]) * dis[col[e]];
}

// Y[N,64] = X[N,K] @ W[K,64].  Block: 256 thr = 16 rows x 64 cols, 4 rows/thread.
template <int K>
__global__ __launch_bounds__(256) void gemm_k(const float* __restrict__ X,
                                              const float* __restrict__ W,
                                              float* __restrict__ Y, int N) {
    __shared__ float xs[16 * K];
    const int tid = threadIdx.x;
    const int row0 = blockIdx.x * 16;
    // stage 16 contiguous rows (row-major -> fully coalesced)
    for (int idx = tid; idx < 16 * K; idx += 256) {
        int r = row0 + idx / K;
        xs[idx] = (r < N) ? X[(size_t)row0 * K + idx] : 0.0f;
    }
    __syncthreads();
    const int c  = tid & 63;
    const int rg = tid >> 6;              // 0..3 -> rows rg*4 .. rg*4+3
    const float* xp = xs + rg * 4 * K;
    float a0 = 0.f, a1 = 0.f, a2 = 0.f, a3 = 0.f;
#pragma unroll
    for (int k = 0; k < K; ++k) {
        float w = W[k * 64 + c];          // coalesced, L1-resident (<=32KB)
        a0 = fmaf(xp[k],         w, a0);  // LDS broadcast reads (no conflicts)
        a1 = fmaf(xp[K + k],     w, a1);
        a2 = fmaf(xp[2 * K + k], w, a2);
        a3 = fmaf(xp[3 * K + k], w, a3);
    }
    int r = row0 + rg * 4;
    if (r < N)     Y[(size_t)r * 64 + c]       = a0;
    if (r + 1 < N) Y[(size_t)(r + 1) * 64 + c] = a1;
    if (r + 2 < N) Y[(size_t)(r + 2) * 64 + c] = a2;
    if (r + 3 < N) Y[(size_t)(r + 3) * 64 + c] = a3;
}

// One wave per edge; lane = feature. agg[col] += norm * xw[row]
__global__ __launch_bounds__(256) void agg_k(const int* __restrict__ row,
                                             const int* __restrict__ col,
                                             const float* __restrict__ norm,
                                             const float* __restrict__ xw,
                                             float* __restrict__ agg, int E) {
    int e = blockIdx.x * 4 + (threadIdx.x >> 6);
    if (e >= E) return;
    int lane = threadIdx.x & 63;
    int r = row[e], c = col[e];
    float nv = norm[e];
    float v = nv * xw[(size_t)r * 64 + lane];   // coalesced 256B gather
    atomicAdd(&agg[(size_t)c * 64 + lane], v);  // coalesced 256B atomic
}

// h = relu(agg + dis^2 * xw + b)   (in place into agg)
__global__ void fin_k(float* __restrict__ agg, const float* __restrict__ xw,
                      const float* __restrict__ dis, const float* __restrict__ b,
                      int N) {
    size_t i = (size_t)blockIdx.x * blockDim.x + threadIdx.x;
    if (i >= (size_t)N * 64) return;
    int node = (int)(i >> 6), j = (int)(i & 63);
    float d = dis[node];
    agg[i] = fmaxf(fmaf(d * d, xw[i], agg[i]) + b[j], 0.0f);
}

// Wave per node: actor logit (shfl reduce) + atomic pool accumulation.
__global__ __launch_bounds__(256) void heads_k(const float* __restrict__ h,
                                               const float* __restrict__ aw,
                                               const float* __restrict__ ab,
                                               const int* __restrict__ batch,
                                               float* __restrict__ logits,
                                               float* __restrict__ sums,
                                               float* __restrict__ counts, int N) {
    int i = blockIdx.x * 4 + (threadIdx.x >> 6);
    if (i >= N) return;
    int lane = threadIdx.x & 63;
    float hv = h[(size_t)i * 64 + lane];
    float p = hv * aw[lane];
    for (int off = 32; off; off >>= 1) p += __shfl_down(p, off);
    int g = batch[i];
    atomicAdd(&sums[g * 64 + lane], hv);
    if (lane == 0) {
        logits[i] = p + ab[0];
        atomicAdd(&counts[g], 1.0f);
    }
}

__global__ void value_k(const float* __restrict__ sums, const float* __restrict__ counts,
                        const float* __restrict__ cw, const float* __restrict__ cb,
                        float* __restrict__ val) {
    int g = blockIdx.x;
    int lane = threadIdx.x;  // block 64
    float cnt = fmaxf(counts[g], 1.0f);
    float p = (sums[g * 64 + lane] / cnt) * cw[lane];
    for (int off = 32; off; off >>= 1) p += __shfl_down(p, off);
    if (lane == 0) val[g] = p + cb[0];
}

extern "C" void kernel_launch(void* const* d_in, const int* in_sizes, int n_in,
                              void* d_out, int out_size, void* d_ws, size_t ws_size,
                              hipStream_t stream) {
    const float* x     = (const float*)d_in[0];
    const int*   ei    = (const int*)d_in[1];
    const float* ea    = (const float*)d_in[2];
    const int*   batch = (const int*)d_in[3];
    const float* W1    = (const float*)d_in[4];
    const float* b1    = (const float*)d_in[5];
    const float* W2    = (const float*)d_in[6];
    const float* b2    = (const float*)d_in[7];
    const float* aw    = (const float*)d_in[8];
    const float* ab    = (const float*)d_in[9];
    const float* cw    = (const float*)d_in[10];
    const float* cb    = (const float*)d_in[11];

    const int N = in_sizes[3];       // batch vector length = num nodes
    const int E = in_sizes[2];       // edge_attr length
    const int H = 64, G = 64;
    const int* row = ei;
    const int* col = ei + E;

    float* ws     = (float*)d_ws;
    float* deg    = ws;                         // N   (becomes dis in place)
    float* norm   = deg + N;                    // E
    float* bufA   = norm + E;                   // N*H  (xw1 -> xw2)
    float* bufB   = bufA + (size_t)N * H;       // N*H  (agg1/h1 -> agg2/h2)
    float* sums   = bufB + (size_t)N * H;       // G*H
    float* counts = sums + G * H;               // G

    float* logits = (float*)d_out;              // N
    float* value  = logits + N;                 // G

    hipMemsetAsync(deg, 0, (size_t)N * 4, stream);
    deg_accum_k<<<(E + TB - 1) / TB, TB, 0, stream>>>(col, ea, deg, E);
    dis_k<<<(N + TB - 1) / TB, TB, 0, stream>>>(deg, N);
    norm_k<<<(E + TB - 1) / TB, TB, 0, stream>>>(row, col, ea, deg, norm, E);

    // ---- layer 1 ----
    gemm_k<128><<<(N + 15) / 16, 256, 0, stream>>>(x, W1, bufA, N);
    hipMemsetAsync(bufB, 0, (size_t)N * H * 4, stream);
    agg_k<<<(E + 3) / 4, 256, 0, stream>>>(row, col, norm, bufA, bufB, E);
    fin_k<<<(int)(((size_t)N * H + 255) / 256), 256, 0, stream>>>(bufB, bufA, deg, b1, N);

    // ---- layer 2 ----
    gemm_k<64><<<(N + 15) / 16, 256, 0, stream>>>(bufB, W2, bufA, N);
    hipMemsetAsync(bufB, 0, (size_t)N * H * 4, stream);   // ordered after gemm read
    agg_k<<<(E + 3) / 4, 256, 0, stream>>>(row, col, norm, bufA, bufB, E);
    fin_k<<<(int)(((size_t)N * H + 255) / 256), 256, 0, stream>>>(bufB, bufA, deg, b2, N);

    // ---- heads ----
    hipMemsetAsync(sums, 0, (size_t)(G * H + G) * 4, stream);
    heads_k<<<(N + 3) / 4, 256, 0, stream>>>(bufB, aw, ab, batch, logits, sums, counts, N);
    value_k<<<G, 64, 0, stream>>>(sums, counts, cw, cb, value);
}

// Round 4
// 1313.933 us; speedup vs baseline: 1.5253x; 1.5253x over previous
//
#include <hip/hip_runtime.h>

// GNNPolicy forward: 2-layer GCN (edge-weighted, symmetric norm, self-loops)
// + per-node actor head + per-graph mean-pool critic head.
// All f32. N=batch nodes, E edges, H=64 hidden, G=64 graphs.

#define TB 256

__global__ void deg_accum_k(const int* __restrict__ col, const float* __restrict__ ea,
                            float* __restrict__ deg, int E) {
    int e = blockIdx.x * blockDim.x + threadIdx.x;
    if (e < E) atomicAdd(&deg[col[e]], fabsf(ea[e]));
}

__global__ void dis_k(float* __restrict__ deg, int N) {
    int i = blockIdx.x * blockDim.x + threadIdx.x;
    if (i < N) deg[i] = rsqrtf(deg[i] + 1.0f);   // deg>=1 always (self-loop)
}

__global__ void norm_k(const int* __restrict__ row, const int* __restrict__ col,
                       const float* __restrict__ ea, const float* __restrict__ dis,
                       float* __restrict__ norm, int E) {
    int e = blockIdx.x * blockDim.x + threadIdx.x;
    if (e < E) norm[e] = dis[row[e]] * fabsf(ea[e]) * dis[col[e]];
}

// Y[N,64] = X[N,K] @ W[K,64].  Block: 256 thr = 16 rows x 64 cols, 4 rows/thread.
template <int K>
__global__ __launch_bounds__(256) void gemm_k(const float* __restrict__ X,
                                              const float* __restrict__ W,
                                              float* __restrict__ Y, int N) {
    __shared__ float xs[16 * K];
    const int tid = threadIdx.x;
    const int row0 = blockIdx.x * 16;
    for (int idx = tid; idx < 16 * K; idx += 256) {
        int r = row0 + idx / K;
        xs[idx] = (r < N) ? X[(size_t)row0 * K + idx] : 0.0f;
    }
    __syncthreads();
    const int c  = tid & 63;
    const int rg = tid >> 6;
    const float* xp = xs + rg * 4 * K;
    float a0 = 0.f, a1 = 0.f, a2 = 0.f, a3 = 0.f;
#pragma unroll
    for (int k = 0; k < K; ++k) {
        float w = W[k * 64 + c];
        a0 = fmaf(xp[k],         w, a0);
        a1 = fmaf(xp[K + k],     w, a1);
        a2 = fmaf(xp[2 * K + k], w, a2);
        a3 = fmaf(xp[3 * K + k], w, a3);
    }
    int r = row0 + rg * 4;
    if (r < N)     Y[(size_t)r * 64 + c]       = a0;
    if (r + 1 < N) Y[(size_t)(r + 1) * 64 + c] = a1;
    if (r + 2 < N) Y[(size_t)(r + 2) * 64 + c] = a2;
    if (r + 3 < N) Y[(size_t)(r + 3) * 64 + c] = a3;
}

// One wave per edge; lane = feature. agg[col] += norm * xw[row]
__global__ __launch_bounds__(256) void agg_k(const int* __restrict__ row,
                                             const int* __restrict__ col,
                                             const float* __restrict__ norm,
                                             const float* __restrict__ xw,
                                             float* __restrict__ agg, int E) {
    int e = blockIdx.x * 4 + (threadIdx.x >> 6);
    if (e >= E) return;
    int lane = threadIdx.x & 63;
    int r = row[e], c = col[e];
    float nv = norm[e];
    float v = nv * xw[(size_t)r * 64 + lane];
    atomicAdd(&agg[(size_t)c * 64 + lane], v);
}

// h = relu(agg + dis^2 * xw + b)   (in place into agg)
__global__ void fin_k(float* __restrict__ agg, const float* __restrict__ xw,
                      const float* __restrict__ dis, const float* __restrict__ b,
                      int N) {
    size_t i = (size_t)blockIdx.x * blockDim.x + threadIdx.x;
    if (i >= (size_t)N * 64) return;
    int node = (int)(i >> 6), j = (int)(i & 63);
    float d = dis[node];
    agg[i] = fmaxf(fmaf(d * d, xw[i], agg[i]) + b[j], 0.0f);
}

// Segmented heads: each wave owns a contiguous node chunk. Lane j keeps a
// register running-sum of feature j for the current graph; flush one coalesced
// 64-lane atomic row per graph TRANSITION (batch is sorted -> ~1 per wave).
// Actor logit per node via shfl reduce (no contention).
__global__ __launch_bounds__(256) void heads_k(const float* __restrict__ h,
                                               const float* __restrict__ aw,
                                               const float* __restrict__ ab,
                                               const int* __restrict__ batch,
                                               float* __restrict__ logits,
                                               float* __restrict__ sums,
                                               float* __restrict__ counts,
                                               int N, int C) {
    int wave = blockIdx.x * 4 + (threadIdx.x >> 6);
    int lane = threadIdx.x & 63;
    int start = wave * C;
    if (start >= N) return;
    int end = min(start + C, N);
    float aww = aw[lane];
    float abv = ab[0];
    int cur = batch[start];
    float acc = 0.f;
    int cnt = 0;
    for (int i = start; i < end; ++i) {
        float hv = h[(size_t)i * 64 + lane];
        float p = hv * aww;
        for (int off = 32; off; off >>= 1) p += __shfl_down(p, off);
        if (lane == 0) logits[i] = p + abv;
        int g = batch[i];                      // wave-uniform
        if (g != cur) {                        // wave-uniform branch
            atomicAdd(&sums[cur * 64 + lane], acc);
            if (lane == 0) atomicAdd(&counts[cur], (float)cnt);
            acc = 0.f; cnt = 0; cur = g;
        }
        acc += hv; ++cnt;
    }
    atomicAdd(&sums[cur * 64 + lane], acc);
    if (lane == 0) atomicAdd(&counts[cur], (float)cnt);
}

__global__ void value_k(const float* __restrict__ sums, const float* __restrict__ counts,
                        const float* __restrict__ cw, const float* __restrict__ cb,
                        float* __restrict__ val) {
    int g = blockIdx.x;
    int lane = threadIdx.x;  // block 64
    float cnt = fmaxf(counts[g], 1.0f);
    float p = (sums[g * 64 + lane] / cnt) * cw[lane];
    for (int off = 32; off; off >>= 1) p += __shfl_down(p, off);
    if (lane == 0) val[g] = p + cb[0];
}

extern "C" void kernel_launch(void* const* d_in, const int* in_sizes, int n_in,
                              void* d_out, int out_size, void* d_ws, size_t ws_size,
                              hipStream_t stream) {
    const float* x     = (const float*)d_in[0];
    const int*   ei    = (const int*)d_in[1];
    const float* ea    = (const float*)d_in[2];
    const int*   batch = (const int*)d_in[3];
    const float* W1    = (const float*)d_in[4];
    const float* b1    = (const float*)d_in[5];
    const float* W2    = (const float*)d_in[6];
    const float* b2    = (const float*)d_in[7];
    const float* aw    = (const float*)d_in[8];
    const float* ab    = (const float*)d_in[9];
    const float* cw    = (const float*)d_in[10];
    const float* cb    = (const float*)d_in[11];

    const int N = in_sizes[3];
    const int E = in_sizes[2];
    const int H = 64, G = 64;
    const int* row = ei;
    const int* col = ei + E;

    float* ws     = (float*)d_ws;
    float* deg    = ws;                         // N   (becomes dis in place)
    float* norm   = deg + N;                    // E
    float* bufA   = norm + E;                   // N*H  (xw1 -> xw2)
    float* bufB   = bufA + (size_t)N * H;       // N*H  (agg1/h1 -> agg2/h2)
    float* sums   = bufB + (size_t)N * H;       // G*H
    float* counts = sums + G * H;               // G

    float* logits = (float*)d_out;              // N
    float* value  = logits + N;                 // G

    hipMemsetAsync(deg, 0, (size_t)N * 4, stream);
    deg_accum_k<<<(E + TB - 1) / TB, TB, 0, stream>>>(col, ea, deg, E);
    dis_k<<<(N + TB - 1) / TB, TB, 0, stream>>>(deg, N);
    norm_k<<<(E + TB - 1) / TB, TB, 0, stream>>>(row, col, ea, deg, norm, E);

    // ---- layer 1 ----
    gemm_k<128><<<(N + 15) / 16, 256, 0, stream>>>(x, W1, bufA, N);
    hipMemsetAsync(bufB, 0, (size_t)N * H * 4, stream);
    agg_k<<<(E + 3) / 4, 256, 0, stream>>>(row, col, norm, bufA, bufB, E);
    fin_k<<<(int)(((size_t)N * H + 255) / 256), 256, 0, stream>>>(bufB, bufA, deg, b1, N);

    // ---- layer 2 ----
    gemm_k<64><<<(N + 15) / 16, 256, 0, stream>>>(bufB, W2, bufA, N);
    hipMemsetAsync(bufB, 0, (size_t)N * H * 4, stream);
    agg_k<<<(E + 3) / 4, 256, 0, stream>>>(row, col, norm, bufA, bufB, E);
    fin_k<<<(int)(((size_t)N * H + 255) / 256), 256, 0, stream>>>(bufB, bufA, deg, b2, N);

    // ---- heads (segmented; batch sorted) ----
    hipMemsetAsync(sums, 0, (size_t)(G * H + G) * 4, stream);
    const int WAVES = 4096;                     // 1024 blocks x 4 waves
    const int C = (N + WAVES - 1) / WAVES;      // ~25 nodes per wave
    heads_k<<<WAVES / 4, 256, 0, stream>>>(bufB, aw, ab, batch, logits, sums, counts, N, C);
    value_k<<<G, 64, 0, stream>>>(sums, counts, cw, cb, value);
}

// Round 5
// 911.209 us; speedup vs baseline: 2.1995x; 1.4420x over previous
//
#include <hip/hip_runtime.h>

// GNNPolicy forward: 2-layer GCN (edge-weighted, symmetric norm, self-loops)
// + per-node actor head + per-graph mean-pool critic head.
// All f32. N=batch nodes, E edges, H=64 hidden, G=64 graphs.

#define TB 256

__global__ void deg_accum_k(const int* __restrict__ col, const float* __restrict__ ea,
                            float* __restrict__ deg, int E) {
    int e = blockIdx.x * blockDim.x + threadIdx.x;
    if (e < E) atomicAdd(&deg[col[e]], fabsf(ea[e]));
}

__global__ void dis_k(float* __restrict__ deg, int N) {
    int i = blockIdx.x * blockDim.x + threadIdx.x;
    if (i < N) deg[i] = rsqrtf(deg[i] + 1.0f);   // deg>=1 always (self-loop)
}

__global__ void norm_k(const int* __restrict__ row, const int* __restrict__ col,
                       const float* __restrict__ ea, const float* __restrict__ dis,
                       float* __restrict__ norm, int E) {
    int e = blockIdx.x * blockDim.x + threadIdx.x;
    if (e < E) norm[e] = dis[row[e]] * fabsf(ea[e]) * dis[col[e]];
}

// Y[N,64] = X[N,K] @ W[K,64].  Block: 256 thr = 16 rows x 64 cols, 4 rows/thread.
// k-loop vectorized by 4 (float4 LDS broadcast reads), unroll capped to avoid
// the VGPR blowup/spill that full unroll caused (256 VGPR, 762MB scratch wr).
template <int K>
__global__ __launch_bounds__(256) void gemm_k(const float* __restrict__ X,
                                              const float* __restrict__ W,
                                              float* __restrict__ Y, int N) {
    __shared__ float xs[16 * K];
    const int tid = threadIdx.x;
    const int row0 = blockIdx.x * 16;
    // stage 16 contiguous rows, float4-vectorized (rows are 16B-aligned: K%4==0)
    const float4* X4 = reinterpret_cast<const float4*>(X + (size_t)row0 * K);
    float4* xs4 = reinterpret_cast<float4*>(xs);
    for (int idx = tid; idx < 16 * K / 4; idx += 256) {
        int r = row0 + (idx * 4) / K;
        xs4[idx] = (r < N) ? X4[idx] : float4{0.f, 0.f, 0.f, 0.f};
    }
    __syncthreads();
    const int c  = tid & 63;
    const int rg = tid >> 6;
    const float4* xp0 = reinterpret_cast<const float4*>(xs + (rg * 4 + 0) * K);
    const float4* xp1 = reinterpret_cast<const float4*>(xs + (rg * 4 + 1) * K);
    const float4* xp2 = reinterpret_cast<const float4*>(xs + (rg * 4 + 2) * K);
    const float4* xp3 = reinterpret_cast<const float4*>(xs + (rg * 4 + 3) * K);
    float a0 = 0.f, a1 = 0.f, a2 = 0.f, a3 = 0.f;
#pragma unroll 2
    for (int k4 = 0; k4 < K / 4; ++k4) {
        float4 x0 = xp0[k4], x1 = xp1[k4], x2 = xp2[k4], x3 = xp3[k4];
        const float* wp = W + k4 * 4 * 64 + c;       // coalesced, L1-resident
        float w0 = wp[0], w1 = wp[64], w2 = wp[128], w3 = wp[192];
        a0 = fmaf(x0.x, w0, a0); a0 = fmaf(x0.y, w1, a0);
        a0 = fmaf(x0.z, w2, a0); a0 = fmaf(x0.w, w3, a0);
        a1 = fmaf(x1.x, w0, a1); a1 = fmaf(x1.y, w1, a1);
        a1 = fmaf(x1.z, w2, a1); a1 = fmaf(x1.w, w3, a1);
        a2 = fmaf(x2.x, w0, a2); a2 = fmaf(x2.y, w1, a2);
        a2 = fmaf(x2.z, w2, a2); a2 = fmaf(x2.w, w3, a2);
        a3 = fmaf(x3.x, w0, a3); a3 = fmaf(x3.y, w1, a3);
        a3 = fmaf(x3.z, w2, a3); a3 = fmaf(x3.w, w3, a3);
    }
    int r = row0 + rg * 4;
    if (r < N)     Y[(size_t)r * 64 + c]       = a0;
    if (r + 1 < N) Y[(size_t)(r + 1) * 64 + c] = a1;
    if (r + 2 < N) Y[(size_t)(r + 2) * 64 + c] = a2;
    if (r + 3 < N) Y[(size_t)(r + 3) * 64 + c] = a3;
}

// One wave per edge; lane = feature. agg[col] += norm * xw[row]
__global__ __launch_bounds__(256) void agg_k(const int* __restrict__ row,
                                             const int* __restrict__ col,
                                             const float* __restrict__ norm,
                                             const float* __restrict__ xw,
                                             float* __restrict__ agg, int E) {
    int e = blockIdx.x * 4 + (threadIdx.x >> 6);
    if (e >= E) return;
    int lane = threadIdx.x & 63;
    int r = row[e], c = col[e];
    float nv = norm[e];
    float v = nv * xw[(size_t)r * 64 + lane];
    atomicAdd(&agg[(size_t)c * 64 + lane], v);
}

// h = relu(agg + dis^2 * xw + b)   (in place into agg)
__global__ void fin_k(float* __restrict__ agg, const float* __restrict__ xw,
                      const float* __restrict__ dis, const float* __restrict__ b,
                      int N) {
    size_t i = (size_t)blockIdx.x * blockDim.x + threadIdx.x;
    if (i >= (size_t)N * 64) return;
    int node = (int)(i >> 6), j = (int)(i & 63);
    float d = dis[node];
    agg[i] = fmaxf(fmaf(d * d, xw[i], agg[i]) + b[j], 0.0f);
}

// Segmented heads: each wave owns a contiguous node chunk. Lane j keeps a
// register running-sum of feature j for the current graph; flush one coalesced
// 64-lane atomic row per graph TRANSITION (batch is sorted -> ~1 per wave).
__global__ __launch_bounds__(256) void heads_k(const float* __restrict__ h,
                                               const float* __restrict__ aw,
                                               const float* __restrict__ ab,
                                               const int* __restrict__ batch,
                                               float* __restrict__ logits,
                                               float* __restrict__ sums,
                                               float* __restrict__ counts,
                                               int N, int C) {
    int wave = blockIdx.x * 4 + (threadIdx.x >> 6);
    int lane = threadIdx.x & 63;
    int start = wave * C;
    if (start >= N) return;
    int end = min(start + C, N);
    float aww = aw[lane];
    float abv = ab[0];
    int cur = batch[start];
    float acc = 0.f;
    int cnt = 0;
    for (int i = start; i < end; ++i) {
        float hv = h[(size_t)i * 64 + lane];
        float p = hv * aww;
        for (int off = 32; off; off >>= 1) p += __shfl_down(p, off);
        if (lane == 0) logits[i] = p + abv;
        int g = batch[i];                      // wave-uniform
        if (g != cur) {                        // wave-uniform branch
            atomicAdd(&sums[cur * 64 + lane], acc);
            if (lane == 0) atomicAdd(&counts[cur], (float)cnt);
            acc = 0.f; cnt = 0; cur = g;
        }
        acc += hv; ++cnt;
    }
    atomicAdd(&sums[cur * 64 + lane], acc);
    if (lane == 0) atomicAdd(&counts[cur], (float)cnt);
}

__global__ void value_k(const float* __restrict__ sums, const float* __restrict__ counts,
                        const float* __restrict__ cw, const float* __restrict__ cb,
                        float* __restrict__ val) {
    int g = blockIdx.x;
    int lane = threadIdx.x;  // block 64
    float cnt = fmaxf(counts[g], 1.0f);
    float p = (sums[g * 64 + lane] / cnt) * cw[lane];
    for (int off = 32; off; off >>= 1) p += __shfl_down(p, off);
    if (lane == 0) val[g] = p + cb[0];
}

extern "C" void kernel_launch(void* const* d_in, const int* in_sizes, int n_in,
                              void* d_out, int out_size, void* d_ws, size_t ws_size,
                              hipStream_t stream) {
    const float* x     = (const float*)d_in[0];
    const int*   ei    = (const int*)d_in[1];
    const float* ea    = (const float*)d_in[2];
    const int*   batch = (const int*)d_in[3];
    const float* W1    = (const float*)d_in[4];
    const float* b1    = (const float*)d_in[5];
    const float* W2    = (const float*)d_in[6];
    const float* b2    = (const float*)d_in[7];
    const float* aw    = (const float*)d_in[8];
    const float* ab    = (const float*)d_in[9];
    const float* cw    = (const float*)d_in[10];
    const float* cb    = (const float*)d_in[11];

    const int N = in_sizes[3];
    const int E = in_sizes[2];
    const int H = 64, G = 64;
    const int* row = ei;
    const int* col = ei + E;

    float* ws     = (float*)d_ws;
    float* deg    = ws;                         // N   (becomes dis in place)
    float* norm   = deg + N;                    // E
    float* bufA   = norm + E;                   // N*H  (xw1 -> xw2)
    float* bufB   = bufA + (size_t)N * H;       // N*H  (agg1/h1 -> agg2/h2)
    float* sums   = bufB + (size_t)N * H;       // G*H
    float* counts = sums + G * H;               // G

    float* logits = (float*)d_out;              // N
    float* value  = logits + N;                 // G

    hipMemsetAsync(deg, 0, (size_t)N * 4, stream);
    deg_accum_k<<<(E + TB - 1) / TB, TB, 0, stream>>>(col, ea, deg, E);
    dis_k<<<(N + TB - 1) / TB, TB, 0, stream>>>(deg, N);
    norm_k<<<(E + TB - 1) / TB, TB, 0, stream>>>(row, col, ea, deg, norm, E);

    // ---- layer 1 ----
    gemm_k<128><<<(N + 15) / 16, 256, 0, stream>>>(x, W1, bufA, N);
    hipMemsetAsync(bufB, 0, (size_t)N * H * 4, stream);
    agg_k<<<(E + 3) / 4, 256, 0, stream>>>(row, col, norm, bufA, bufB, E);
    fin_k<<<(int)(((size_t)N * H + 255) / 256), 256, 0, stream>>>(bufB, bufA, deg, b1, N);

    // ---- layer 2 ----
    gemm_k<64><<<(N + 15) / 16, 256, 0, stream>>>(bufB, W2, bufA, N);
    hipMemsetAsync(bufB, 0, (size_t)N * H * 4, stream);
    agg_k<<<(E + 3) / 4, 256, 0, stream>>>(row, col, norm, bufA, bufB, E);
    fin_k<<<(int)(((size_t)N * H + 255) / 256), 256, 0, stream>>>(bufB, bufA, deg, b2, N);

    // ---- heads (segmented; batch sorted) ----
    hipMemsetAsync(sums, 0, (size_t)(G * H + G) * 4, stream);
    const int WAVES = 4096;                     // 1024 blocks x 4 waves
    const int C = (N + WAVES - 1) / WAVES;      // ~25 nodes per wave
    heads_k<<<WAVES / 4, 256, 0, stream>>>(bufB, aw, ab, batch, logits, sums, counts, N, C);
    value_k<<<G, 64, 0, stream>>>(sums, counts, cw, cb, value);
}

// Round 6
// 485.395 us; speedup vs baseline: 4.1289x; 1.8773x over previous
//
#include <hip/hip_runtime.h>

// GNNPolicy forward: 2-layer GCN (edge-weighted, symmetric norm, self-loops)
// + per-node actor head + per-graph mean-pool critic head.
// All f32. N=100K nodes, E=1.6M edges, H=64 hidden, G=64 graphs.
// Aggregation via CSR-by-destination gather (no f32 scatter atomics).

#define TB 256
#define SB 256      // scan block threads
#define SI 16       // scan items per thread (4096 per block, shift 12)

__global__ void deg_cnt_k(const int* __restrict__ col, const float* __restrict__ ea,
                          float* __restrict__ deg, int* __restrict__ cnt, int E) {
    int e = blockIdx.x * blockDim.x + threadIdx.x;
    if (e < E) {
        int c = col[e];
        atomicAdd(&deg[c], fabsf(ea[e]));
        atomicAdd(&cnt[c], 1);
    }
}

__global__ void dis_k(float* __restrict__ deg, int N) {
    int i = blockIdx.x * blockDim.x + threadIdx.x;
    if (i < N) deg[i] = rsqrtf(deg[i] + 1.0f);   // deg>=1 always (self-loop)
}

// ---- 3-kernel exclusive scan of cnt -> ptr ----
__global__ __launch_bounds__(SB) void scan1_k(const int* __restrict__ cnt,
                                              int* __restrict__ ptr,
                                              int* __restrict__ part, int N) {
    __shared__ int ts[SB];
    int t = threadIdx.x;
    int off = blockIdx.x * SB * SI + t * SI;
    int local[SI];
    int s = 0;
#pragma unroll
    for (int i = 0; i < SI; ++i) {
        int v = (off + i < N) ? cnt[off + i] : 0;
        local[i] = s; s += v;
    }
    ts[t] = s; __syncthreads();
    for (int d = 1; d < SB; d <<= 1) {
        int v = (t >= d) ? ts[t - d] : 0;
        __syncthreads();
        ts[t] += v;
        __syncthreads();
    }
    int texcl = t ? ts[t - 1] : 0;
#pragma unroll
    for (int i = 0; i < SI; ++i)
        if (off + i < N) ptr[off + i] = texcl + local[i];
    if (t == SB - 1) part[blockIdx.x] = ts[SB - 1];
}

__global__ __launch_bounds__(1024) void scan2_k(int* __restrict__ part, int NB) {
    __shared__ int ts[1024];
    int t = threadIdx.x;
    ts[t] = (t < NB) ? part[t] : 0; __syncthreads();
    for (int d = 1; d < 1024; d <<= 1) {
        int v = (t >= d) ? ts[t - d] : 0;
        __syncthreads();
        ts[t] += v;
        __syncthreads();
    }
    if (t < NB) part[t] = t ? ts[t - 1] : 0;   // exclusive
}

__global__ void scan3_k(int* __restrict__ ptr, int* __restrict__ cursor,
                        const int* __restrict__ part, int N) {
    int i = blockIdx.x * blockDim.x + threadIdx.x;
    if (i < N) {
        int p = ptr[i] + part[i >> 12];        // 4096 elems per scan1 block
        ptr[i] = p;
        cursor[i] = p;
    }
}

// scatter edges into CSR order, computing norm inline: rec = (row, norm)
__global__ void scatter_k(const int* __restrict__ row, const int* __restrict__ col,
                          const float* __restrict__ ea, const float* __restrict__ dis,
                          int* __restrict__ cursor, uint2* __restrict__ rec, int E) {
    int e = blockIdx.x * blockDim.x + threadIdx.x;
    if (e >= E) return;
    int r = row[e], c = col[e];
    float nv = dis[r] * fabsf(ea[e]) * dis[c];
    int pos = atomicAdd(&cursor[c], 1);
    rec[pos] = make_uint2((unsigned)r, __float_as_uint(nv));
}

// Y[N,64] = X[N,K] @ W[K,64].  Block: 256 thr = 16 rows x 64 cols, 4 rows/thread.
template <int K>
__global__ __launch_bounds__(256) void gemm_k(const float* __restrict__ X,
                                              const float* __restrict__ W,
                                              float* __restrict__ Y, int N) {
    __shared__ float xs[16 * K];
    const int tid = threadIdx.x;
    const int row0 = blockIdx.x * 16;
    const float4* X4 = reinterpret_cast<const float4*>(X + (size_t)row0 * K);
    float4* xs4 = reinterpret_cast<float4*>(xs);
    for (int idx = tid; idx < 16 * K / 4; idx += 256) {
        int r = row0 + (idx * 4) / K;
        xs4[idx] = (r < N) ? X4[idx] : float4{0.f, 0.f, 0.f, 0.f};
    }
    __syncthreads();
    const int c  = tid & 63;
    const int rg = tid >> 6;
    const float4* xp0 = reinterpret_cast<const float4*>(xs + (rg * 4 + 0) * K);
    const float4* xp1 = reinterpret_cast<const float4*>(xs + (rg * 4 + 1) * K);
    const float4* xp2 = reinterpret_cast<const float4*>(xs + (rg * 4 + 2) * K);
    const float4* xp3 = reinterpret_cast<const float4*>(xs + (rg * 4 + 3) * K);
    float a0 = 0.f, a1 = 0.f, a2 = 0.f, a3 = 0.f;
#pragma unroll 2
    for (int k4 = 0; k4 < K / 4; ++k4) {
        float4 x0 = xp0[k4], x1 = xp1[k4], x2 = xp2[k4], x3 = xp3[k4];
        const float* wp = W + k4 * 4 * 64 + c;
        float w0 = wp[0], w1 = wp[64], w2 = wp[128], w3 = wp[192];
        a0 = fmaf(x0.x, w0, a0); a0 = fmaf(x0.y, w1, a0);
        a0 = fmaf(x0.z, w2, a0); a0 = fmaf(x0.w, w3, a0);
        a1 = fmaf(x1.x, w0, a1); a1 = fmaf(x1.y, w1, a1);
        a1 = fmaf(x1.z, w2, a1); a1 = fmaf(x1.w, w3, a1);
        a2 = fmaf(x2.x, w0, a2); a2 = fmaf(x2.y, w1, a2);
        a2 = fmaf(x2.z, w2, a2); a2 = fmaf(x2.w, w3, a2);
        a3 = fmaf(x3.x, w0, a3); a3 = fmaf(x3.y, w1, a3);
        a3 = fmaf(x3.z, w2, a3); a3 = fmaf(x3.w, w3, a3);
    }
    int r = row0 + rg * 4;
    if (r < N)     Y[(size_t)r * 64 + c]       = a0;
    if (r + 1 < N) Y[(size_t)(r + 1) * 64 + c] = a1;
    if (r + 2 < N) Y[(size_t)(r + 2) * 64 + c] = a2;
    if (r + 3 < N) Y[(size_t)(r + 3) * 64 + c] = a3;
}

// CSR gather aggregation fused with self-loop + bias + ReLU.
// Wave per node, lane = feature. No atomics, no memset, no separate fin pass.
__global__ __launch_bounds__(256) void agg_fin_k(const int* __restrict__ ptr,
                                                 const int* __restrict__ cnt,
                                                 const uint2* __restrict__ rec,
                                                 const float* __restrict__ xw,
                                                 const float* __restrict__ dis,
                                                 const float* __restrict__ bias,
                                                 float* __restrict__ h, int N) {
    int n = blockIdx.x * 4 + (threadIdx.x >> 6);
    if (n >= N) return;
    int lane = threadIdx.x & 63;
    int base = ptr[n], num = cnt[n];
    float acc = 0.f;
    int k = 0;
    for (; k + 3 < num; k += 4) {              // 4 gathers in flight (ILP)
        uint2 e0 = rec[base + k],     e1 = rec[base + k + 1];
        uint2 e2 = rec[base + k + 2], e3 = rec[base + k + 3];
        acc = fmaf(__uint_as_float(e0.y), xw[(size_t)e0.x * 64 + lane], acc);
        acc = fmaf(__uint_as_float(e1.y), xw[(size_t)e1.x * 64 + lane], acc);
        acc = fmaf(__uint_as_float(e2.y), xw[(size_t)e2.x * 64 + lane], acc);
        acc = fmaf(__uint_as_float(e3.y), xw[(size_t)e3.x * 64 + lane], acc);
    }
    for (; k < num; ++k) {
        uint2 e0 = rec[base + k];
        acc = fmaf(__uint_as_float(e0.y), xw[(size_t)e0.x * 64 + lane], acc);
    }
    float d = dis[n];
    h[(size_t)n * 64 + lane] =
        fmaxf(fmaf(d * d, xw[(size_t)n * 64 + lane], acc) + bias[lane], 0.0f);
}

// Segmented heads: wave per contiguous node chunk; register pool accumulation,
// one coalesced atomic row per graph transition (batch is sorted).
__global__ __launch_bounds__(256) void heads_k(const float* __restrict__ h,
                                               const float* __restrict__ aw,
                                               const float* __restrict__ ab,
                                               const int* __restrict__ batch,
                                               float* __restrict__ logits,
                                               float* __restrict__ sums,
                                               float* __restrict__ counts,
                                               int N, int C) {
    int wave = blockIdx.x * 4 + (threadIdx.x >> 6);
    int lane = threadIdx.x & 63;
    int start = wave * C;
    if (start >= N) return;
    int end = min(start + C, N);
    float aww = aw[lane];
    float abv = ab[0];
    int cur = batch[start];
    float acc = 0.f;
    int cnt = 0;
    for (int i = start; i < end; ++i) {
        float hv = h[(size_t)i * 64 + lane];
        float p = hv * aww;
        for (int off = 32; off; off >>= 1) p += __shfl_down(p, off);
        if (lane == 0) logits[i] = p + abv;
        int g = batch[i];                      // wave-uniform
        if (g != cur) {
            atomicAdd(&sums[cur * 64 + lane], acc);
            if (lane == 0) atomicAdd(&counts[cur], (float)cnt);
            acc = 0.f; cnt = 0; cur = g;
        }
        acc += hv; ++cnt;
    }
    atomicAdd(&sums[cur * 64 + lane], acc);
    if (lane == 0) atomicAdd(&counts[cur], (float)cnt);
}

__global__ void value_k(const float* __restrict__ sums, const float* __restrict__ counts,
                        const float* __restrict__ cw, const float* __restrict__ cb,
                        float* __restrict__ val) {
    int g = blockIdx.x;
    int lane = threadIdx.x;  // block 64
    float cnt = fmaxf(counts[g], 1.0f);
    float p = (sums[g * 64 + lane] / cnt) * cw[lane];
    for (int off = 32; off; off >>= 1) p += __shfl_down(p, off);
    if (lane == 0) val[g] = p + cb[0];
}

extern "C" void kernel_launch(void* const* d_in, const int* in_sizes, int n_in,
                              void* d_out, int out_size, void* d_ws, size_t ws_size,
                              hipStream_t stream) {
    const float* x     = (const float*)d_in[0];
    const int*   ei    = (const int*)d_in[1];
    const float* ea    = (const float*)d_in[2];
    const int*   batch = (const int*)d_in[3];
    const float* W1    = (const float*)d_in[4];
    const float* b1    = (const float*)d_in[5];
    const float* W2    = (const float*)d_in[6];
    const float* b2    = (const float*)d_in[7];
    const float* aw    = (const float*)d_in[8];
    const float* ab    = (const float*)d_in[9];
    const float* cw    = (const float*)d_in[10];
    const float* cb    = (const float*)d_in[11];

    const int N = in_sizes[3];
    const int E = in_sizes[2];
    const int H = 64, G = 64;
    const int* row = ei;
    const int* col = ei + E;

    // workspace layout (rec offset is 8B-aligned: 4*(4N+1024) with N even)
    float* deg    = (float*)d_ws;               // N (becomes dis in place)
    int*   cnt    = (int*)(deg + N);            // N
    int*   ptr    = cnt + N;                    // N
    int*   cursor = ptr + N;                    // N
    int*   part   = cursor + N;                 // 1024 scan partials
    uint2* rec    = (uint2*)(part + 1024);      // E  (row, norm)
    float* bufA   = (float*)(rec + E);          // N*H
    float* bufB   = bufA + (size_t)N * H;       // N*H
    float* sums   = bufB + (size_t)N * H;       // G*H
    float* counts = sums + G * H;               // G

    float* logits = (float*)d_out;              // N
    float* value  = logits + N;                 // G

    const int NB = (N + SB * SI - 1) / (SB * SI);   // scan1 blocks (<=1024)

    // ---- CSR build (shared by both layers) ----
    hipMemsetAsync(deg, 0, (size_t)2 * N * 4, stream);   // deg + cnt
    deg_cnt_k<<<(E + TB - 1) / TB, TB, 0, stream>>>(col, ea, deg, cnt, E);
    dis_k<<<(N + TB - 1) / TB, TB, 0, stream>>>(deg, N);
    scan1_k<<<NB, SB, 0, stream>>>(cnt, ptr, part, N);
    scan2_k<<<1, 1024, 0, stream>>>(part, NB);
    scan3_k<<<(N + TB - 1) / TB, TB, 0, stream>>>(ptr, cursor, part, N);
    scatter_k<<<(E + TB - 1) / TB, TB, 0, stream>>>(row, col, ea, deg, cursor, rec, E);

    // ---- layer 1 ----
    gemm_k<128><<<(N + 15) / 16, 256, 0, stream>>>(x, W1, bufA, N);
    agg_fin_k<<<(N + 3) / 4, 256, 0, stream>>>(ptr, cnt, rec, bufA, deg, b1, bufB, N);

    // ---- layer 2 ----
    gemm_k<64><<<(N + 15) / 16, 256, 0, stream>>>(bufB, W2, bufA, N);
    agg_fin_k<<<(N + 3) / 4, 256, 0, stream>>>(ptr, cnt, rec, bufA, deg, b2, bufB, N);

    // ---- heads (segmented; batch sorted) ----
    hipMemsetAsync(sums, 0, (size_t)(G * H + G) * 4, stream);
    const int WAVES = 4096;
    const int C = (N + WAVES - 1) / WAVES;
    heads_k<<<WAVES / 4, 256, 0, stream>>>(bufB, aw, ab, batch, logits, sums, counts, N, C);
    value_k<<<G, 64, 0, stream>>>(sums, counts, cw, cb, value);
}